// Round 6
// baseline (353.473 us; speedup 1.0000x reference)
//
#include <hip/hip_runtime.h>
#include <hip/hip_bf16.h>

#define N_NODES 100000
#define N_EDGES 640000
#define IN_F 256
#define HD 128   // HEADS * OUT_FEATS
#define BM 64

using f32x4 = __attribute__((ext_vector_type(4))) float;
using s8v   = __attribute__((ext_vector_type(8))) short;

__device__ __forceinline__ short bf16rn(float x) {
  unsigned u = __builtin_bit_cast(unsigned, x);
  return (short)((u + 0x7FFFu + ((u >> 16) & 1u)) >> 16);
}
__device__ __forceinline__ float bf16tof(short h) {
  unsigned u = ((unsigned)(unsigned short)h) << 16;
  return __builtin_bit_cast(float, u);
}

typedef const __attribute__((address_space(1))) void gvoid;
typedef __attribute__((address_space(3))) void lvoid;
__device__ __forceinline__ void gl_lds16(const void* g, char* l) {
  __builtin_amdgcn_global_load_lds((gvoid*)g, (lvoid*)l, 16, 0, 0);
}

// ---- one-time: W[256][128] -> Bth[128][256] bf16 (transposed, hi only) ----
__global__ __launch_bounds__(256) void prep_b(const float* __restrict__ W,
                                              short* __restrict__ Bth)
{
  int c = blockIdx.x;      // 128 cols
  int k = threadIdx.x;     // 256 k
  Bth[(size_t)c * IN_F + k] = bf16rn(W[(size_t)k * HD + c]);
}

// ---- one-time: Bx[16][256]: cols 0-3 = W@attn_l, 4-7 = W@attn_r, 8-15 = 0 ----
__global__ __launch_bounds__(256) void prep_x(const float* __restrict__ W,
    const float* __restrict__ al, const float* __restrict__ ar,
    short* __restrict__ Bxh)
{
  int c = blockIdx.x;      // 16
  int k = threadIdx.x;     // 256
  float v = 0.f;
  if (c < 8) {
    int h = c & 3;
    const float* att = (c < 4) ? al : ar;
    #pragma unroll
    for (int d = 0; d < 32; d++)
      v += W[(size_t)k * HD + h * 32 + d] * att[h * 32 + d];
  }
  Bxh[(size_t)c * IN_F + k] = bf16rn(v);
}

// ---- staging: global_load_lds, chunk layout [k-group][row] of 16B units ----
// A: 64 rows x 32 f32 = 8KB = 8 ops (op o = kg, rows = lane)
// B: 128 cols x 32k bf16 = 8KB = 8 ops (op j: c=(j&1)*64+lane, lg=j>>1)
// X: 16 cols x 32k bf16 = 1KB = 1 op (chunk = lane)
__device__ __forceinline__ void stage_tile(char* lds, int wid, int lane, int kt,
    const float* feat, const short* Bth, const short* Bxh, int rb, int M)
{
  const int k0 = kt * 32;
  char* Ab = lds + (kt & 1) * 8192;
  char* Bb = lds + 16384 + (kt & 1) * 8192;
  char* Xb = lds + 32768 + (kt & 1) * 1024;
  int gr = rb + lane; if (gr > M - 1) gr = M - 1;   // clamp tail (stores guarded)
  #pragma unroll
  for (int s = 0; s < 4; s++) {
    const int o = wid + s * 4;          // wave-uniform op id, 0..15
    if (o < 8) {
      gl_lds16(feat + (size_t)gr * IN_F + k0 + o * 4, Ab + o * 1024);
    } else {
      int j = o - 8;
      int c = (j & 1) * 64 + lane, lg = j >> 1;
      gl_lds16(Bth + (size_t)c * IN_F + k0 + lg * 8, Bb + j * 1024);
    }
  }
  if (wid == 0) {
    int c = lane & 15, lg = lane >> 4;
    gl_lds16(Bxh + (size_t)c * IN_F + k0 + lg * 8, Xb);
  }
}

// ---- GEMM (bf16x2 MFMA) + fused el/er:  ft[M,128] = feat[M,256] @ W ----
// Block: 64x128 tile, 4 waves of 32x64. 2-phase global_load_lds pipeline.
__global__ __launch_bounds__(256) void gemm_mfma(const float* __restrict__ feat,
    const short* __restrict__ Bth, const short* __restrict__ Bxh,
    float* __restrict__ ft, float* __restrict__ el, float* __restrict__ er, int M)
{
  __shared__ char lds[34816];   // A 2x8K | B 2x8K | X 2x1K -> 4 blocks/CU
  const int wid  = threadIdx.x >> 6;
  const int lane = threadIdx.x & 63;
  const int lr = lane & 15;           // A row / B col within fragment
  const int lg = lane >> 4;           // k-octet / D row group
  const int wm = (wid >> 1) * 32;
  const int wn = (wid & 1) * 64;
  const int rb = blockIdx.x * BM;
  const bool doX = (wid & 1) == 0;    // left-column waves also compute el/er

  f32x4 acc[2][4];
  f32x4 accx[2];
  #pragma unroll
  for (int mi = 0; mi < 2; mi++) {
    accx[mi] = (f32x4){0.f, 0.f, 0.f, 0.f};
    #pragma unroll
    for (int ni = 0; ni < 4; ni++) acc[mi][ni] = (f32x4){0.f, 0.f, 0.f, 0.f};
  }

  stage_tile(lds, wid, lane, 0, feat, Bth, Bxh, rb, M);
  __syncthreads();

  #pragma unroll
  for (int kt = 0; kt < 8; ++kt) {
    if (kt < 7) stage_tile(lds, wid, lane, kt + 1, feat, Bth, Bxh, rb, M);

    const char* Ab = lds + (kt & 1) * 8192;
    const char* Bb = lds + 16384 + (kt & 1) * 8192;
    const char* Xb = lds + 32768 + (kt & 1) * 1024;

    s8v Bf[4];
    #pragma unroll
    for (int ni = 0; ni < 4; ni++)
      Bf[ni] = *(const s8v*)(Bb + (((lg << 7) + wn + ni * 16 + lr) << 4));
    s8v Xf = *(const s8v*)(Xb + (((lg << 4) + lr) << 4));

    #pragma unroll
    for (int mi = 0; mi < 2; mi++) {
      const int row = wm + mi * 16 + lr;
      const float4 a0 = *(const float4*)(Ab + ((((lg * 2 + 0) << 6) + row) << 4));
      const float4 a1 = *(const float4*)(Ab + ((((lg * 2 + 1) << 6) + row) << 4));
      const float av[8] = {a0.x, a0.y, a0.z, a0.w, a1.x, a1.y, a1.z, a1.w};
      s8v ah, alo;
      #pragma unroll
      for (int j = 0; j < 8; j++) {
        short h = bf16rn(av[j]);
        ah[j]  = h;
        alo[j] = bf16rn(av[j] - bf16tof(h));
      }
      #pragma unroll
      for (int ni = 0; ni < 4; ni++) {
        acc[mi][ni] = __builtin_amdgcn_mfma_f32_16x16x32_bf16(ah,  Bf[ni], acc[mi][ni], 0, 0, 0);
        acc[mi][ni] = __builtin_amdgcn_mfma_f32_16x16x32_bf16(alo, Bf[ni], acc[mi][ni], 0, 0, 0);
      }
      if (doX) {
        accx[mi] = __builtin_amdgcn_mfma_f32_16x16x32_bf16(ah,  Xf, accx[mi], 0, 0, 0);
        accx[mi] = __builtin_amdgcn_mfma_f32_16x16x32_bf16(alo, Xf, accx[mi], 0, 0, 0);
      }
    }
    __syncthreads();
  }

  // D layout: col = lane&15, row = (lane>>4)*4 + reg
  #pragma unroll
  for (int mi = 0; mi < 2; mi++) {
    int rbase = rb + wm + mi * 16 + lg * 4;
    #pragma unroll
    for (int ni = 0; ni < 4; ni++) {
      int col = wn + ni * 16 + lr;
      #pragma unroll
      for (int r = 0; r < 4; r++) {
        int grow = rbase + r;
        if (grow < M) ft[(size_t)grow * HD + col] = acc[mi][ni][r];
      }
    }
    if (doX) {
      #pragma unroll
      for (int r = 0; r < 4; r++) {
        int grow = rbase + r;
        if (grow < M) {
          if (lr < 4)      el[(size_t)grow * 4 + lr]       = accx[mi][r];
          else if (lr < 8) er[(size_t)grow * 4 + (lr - 4)] = accx[mi][r];
        }
      }
    }
  }
}

// ---------------- CSR build ----------------
__global__ void deg_kernel(const int* __restrict__ dst, int* __restrict__ deg) {
  int i = blockIdx.x * blockDim.x + threadIdx.x;
  if (i < N_EDGES) atomicAdd(&deg[dst[i]], 1);
}

__global__ __launch_bounds__(256) void scanA(const int* __restrict__ deg,
    int* __restrict__ excl, int* __restrict__ partials, int n)
{
  __shared__ int s[256];
  int t = threadIdx.x;
  int base = blockIdx.x * 1024 + t * 4;
  int d0 = (base + 0 < n) ? deg[base + 0] : 0;
  int d1 = (base + 1 < n) ? deg[base + 1] : 0;
  int d2 = (base + 2 < n) ? deg[base + 2] : 0;
  int d3 = (base + 3 < n) ? deg[base + 3] : 0;
  int sum = d0 + d1 + d2 + d3;
  s[t] = sum; __syncthreads();
  for (int off = 1; off < 256; off <<= 1) {
    int x = 0; if (t >= off) x = s[t - off];
    __syncthreads(); s[t] += x; __syncthreads();
  }
  int e0 = s[t] - sum;
  if (base + 0 < n) excl[base + 0] = e0;
  if (base + 1 < n) excl[base + 1] = e0 + d0;
  if (base + 2 < n) excl[base + 2] = e0 + d0 + d1;
  if (base + 3 < n) excl[base + 3] = e0 + d0 + d1 + d2;
  if (t == 255) partials[blockIdx.x] = s[255];
}

__global__ void scanB(int* partials, int nb) {
  __shared__ int s[128];
  int t = threadIdx.x;
  int v = (t < nb) ? partials[t] : 0;
  s[t] = v; __syncthreads();
  for (int off = 1; off < 128; off <<= 1) {
    int x = 0; if (t >= off) x = s[t - off];
    __syncthreads(); s[t] += x; __syncthreads();
  }
  if (t < nb) partials[t] = s[t] - v;
}

__global__ __launch_bounds__(256) void scanC(int* __restrict__ row_ptr,
    const int* __restrict__ partials, int n, int E)
{
  int t = threadIdx.x;
  int base = blockIdx.x * 1024 + t * 4;
  int add = partials[blockIdx.x];
  #pragma unroll
  for (int j = 0; j < 4; j++) if (base + j < n) row_ptr[base + j] += add;
  if (blockIdx.x == 0 && t == 0) row_ptr[n] = E;
}

__global__ void scatter_kernel(const int* __restrict__ src, const int* __restrict__ dst,
                               const int* __restrict__ row_ptr,
                               int* __restrict__ cursor, int* __restrict__ usrc) {
  int e = blockIdx.x * blockDim.x + threadIdx.x;
  if (e >= N_EDGES) return;
  int d = dst[e];
  int pos = row_ptr[d] + atomicAdd(&cursor[d], 1);
  usrc[pos] = src[e];
}

// ---------------- fused online-softmax + aggregation: one wave per dst node ----------------
__global__ __launch_bounds__(256) void gat_node(const int* __restrict__ row_ptr,
    const int* __restrict__ usrc,
    const float* __restrict__ el, const float* __restrict__ er4,
    const float* __restrict__ ft, float* __restrict__ rst,
    float* __restrict__ lse, int n)
{
  __shared__ int   su[4][64];
  __shared__ float sex[4][64][4];
  const int w = threadIdx.x >> 6;
  const int lane = threadIdx.x & 63;
  const int v = blockIdx.x * 4 + w;
  if (v >= n) return;
  const int s0 = row_ptr[v];
  const int d  = row_ptr[v + 1] - s0;
  const int g  = lane >> 4;

  if (d == 0) {
    *(float2*)(rst + (size_t)v * HD + 2 * lane) = make_float2(0.f, 0.f);
    return;
  }

  const float4 erv = *(const float4*)(er4 + (size_t)v * 4);
  float m0 = -1e30f, m1 = -1e30f, m2 = -1e30f, m3 = -1e30f;
  float den = 0.f;
  float2 acc = make_float2(0.f, 0.f);

  for (int c0 = 0; c0 < d; c0 += 64) {
    const int cd = min(64, d - c0);
    float x0 = -1e30f, x1 = -1e30f, x2 = -1e30f, x3 = -1e30f;
    int u = 0;
    if (lane < cd) {
      u = usrc[s0 + c0 + lane];
      const float4 elv = *(const float4*)(el + (size_t)u * 4);
      x0 = elv.x + erv.x; x0 = x0 > 0.f ? x0 : 0.2f * x0;
      x1 = elv.y + erv.y; x1 = x1 > 0.f ? x1 : 0.2f * x1;
      x2 = elv.z + erv.z; x2 = x2 > 0.f ? x2 : 0.2f * x2;
      x3 = elv.w + erv.w; x3 = x3 > 0.f ? x3 : 0.2f * x3;
    }
    su[w][lane] = u;
    float n0 = x0, n1 = x1, n2 = x2, n3 = x3;
    #pragma unroll
    for (int off = 32; off >= 1; off >>= 1) {
      n0 = fmaxf(n0, __shfl_xor(n0, off));
      n1 = fmaxf(n1, __shfl_xor(n1, off));
      n2 = fmaxf(n2, __shfl_xor(n2, off));
      n3 = fmaxf(n3, __shfl_xor(n3, off));
    }
    n0 = fmaxf(n0, m0); n1 = fmaxf(n1, m1); n2 = fmaxf(n2, m2); n3 = fmaxf(n3, m3);
    float e0 = __expf(x0 - n0), e1 = __expf(x1 - n1);
    float e2 = __expf(x2 - n2), e3 = __expf(x3 - n3);
    sex[w][lane][0] = e0; sex[w][lane][1] = e1;
    sex[w][lane][2] = e2; sex[w][lane][3] = e3;
    float mg = g == 0 ? m0 : g == 1 ? m1 : g == 2 ? m2 : m3;
    float ng = g == 0 ? n0 : g == 1 ? n1 : g == 2 ? n2 : n3;
    float scale = __expf(mg - ng);
    den *= scale; acc.x *= scale; acc.y *= scale;
    m0 = n0; m1 = n1; m2 = n2; m3 = n3;
    asm volatile("s_waitcnt lgkmcnt(0)" ::: "memory");
    #pragma unroll 4
    for (int j = 0; j < cd; ++j) {
      int uu = su[w][j];
      float wgt = sex[w][j][g];
      float2 f = *(const float2*)(ft + (size_t)uu * HD + 2 * lane);
      den += wgt;
      acc.x += wgt * f.x; acc.y += wgt * f.y;
    }
  }
  *(float2*)(rst + (size_t)v * HD + 2 * lane) = make_float2(acc.x / den, acc.y / den);
  if ((lane & 15) == 0) {
    float mg = g == 0 ? m0 : g == 1 ? m1 : g == 2 ? m2 : m3;
    lse[(size_t)v * 4 + g] = mg + __logf(den);
  }
}

// edge-parallel: a[e][h] = exp(leaky(el[src]+er[dst]) - lse[dst][h])
__global__ void norm_kernel(const int* __restrict__ src, const int* __restrict__ dst,
                            const float* __restrict__ el, const float* __restrict__ er,
                            const float* __restrict__ lse, float* __restrict__ a, int E)
{
  int i = blockIdx.x * blockDim.x + threadIdx.x;
  if (i >= E) return;
  int u = src[i], v = dst[i];
  const float4 elv = *(const float4*)(el + (size_t)u * 4);
  const float4 erv = *(const float4*)(er + (size_t)v * 4);
  const float4 ls  = *(const float4*)(lse + (size_t)v * 4);
  float x0 = elv.x + erv.x; x0 = x0 > 0.f ? x0 : 0.2f * x0;
  float x1 = elv.y + erv.y; x1 = x1 > 0.f ? x1 : 0.2f * x1;
  float x2 = elv.z + erv.z; x2 = x2 > 0.f ? x2 : 0.2f * x2;
  float x3 = elv.w + erv.w; x3 = x3 > 0.f ? x3 : 0.2f * x3;
  float4 o;
  o.x = __expf(x0 - ls.x); o.y = __expf(x1 - ls.y);
  o.z = __expf(x2 - ls.z); o.w = __expf(x3 - ls.w);
  *(float4*)(a + (size_t)i * 4) = o;
}

extern "C" void kernel_launch(void* const* d_in, const int* in_sizes, int n_in,
                              void* d_out, int out_size, void* d_ws, size_t ws_size,
                              hipStream_t stream)
{
  const float* feat = (const float*)d_in[0];
  const float* W    = (const float*)d_in[1];
  const float* al   = (const float*)d_in[2];
  const float* ar   = (const float*)d_in[3];
  const int*   src  = (const int*)d_in[4];
  const int*   dst  = (const int*)d_in[5];
  float* rst   = (float*)d_out;
  float* a_out = rst + (size_t)N_NODES * HD;

  char* w = (char*)d_ws;
  auto alloc = [&](size_t bytes) { char* p = w; w += (bytes + 255) & ~(size_t)255; return p; };
  float* ft      = (float*)alloc((size_t)N_NODES * HD * 4);
  float* el      = (float*)alloc((size_t)N_NODES * 4 * 4);
  float* er      = (float*)alloc((size_t)N_NODES * 4 * 4);
  float* lse     = (float*)alloc((size_t)N_NODES * 4 * 4);
  int*   deg     = (int*)alloc((size_t)N_NODES * 4);
  int*   row_ptr = (int*)alloc(((size_t)N_NODES + 1) * 4);
  int*   cursor  = (int*)alloc((size_t)N_NODES * 4);
  int*   partials= (int*)alloc(1024);
  int*   usrc    = (int*)alloc((size_t)N_EDGES * 4);
  short* Bth     = (short*)alloc((size_t)HD * IN_F * 2);
  short* Bxh     = (short*)alloc((size_t)16 * IN_F * 2);

  hipMemsetAsync(deg, 0, N_NODES * 4, stream);
  hipMemsetAsync(cursor, 0, N_NODES * 4, stream);

  prep_b<<<128, 256, 0, stream>>>(W, Bth);
  prep_x<<<16, 256, 0, stream>>>(W, al, ar, Bxh);
  gemm_mfma<<<(N_NODES + BM - 1) / BM, 256, 0, stream>>>(feat, Bth, Bxh, ft, el, er, N_NODES);
  deg_kernel<<<(N_EDGES + 255) / 256, 256, 0, stream>>>(dst, deg);
  scanA<<<98, 256, 0, stream>>>(deg, row_ptr, partials, N_NODES);
  scanB<<<1, 128, 0, stream>>>(partials, 98);
  scanC<<<98, 256, 0, stream>>>(row_ptr, partials, N_NODES, N_EDGES);
  scatter_kernel<<<(N_EDGES + 255) / 256, 256, 0, stream>>>(src, dst, row_ptr, cursor, usrc);
  gat_node<<<(N_NODES + 3) / 4, 256, 0, stream>>>(row_ptr, usrc, el, er, ft, rst, lse, N_NODES);
  norm_kernel<<<(N_EDGES + 255) / 256, 256, 0, stream>>>(src, dst, el, er, lse, a_out, N_EDGES);
}

// Round 7
// 351.249 us; speedup vs baseline: 1.0063x; 1.0063x over previous
//
#include <hip/hip_runtime.h>
#include <hip/hip_bf16.h>

#define N_NODES 100000
#define N_EDGES 640000
#define IN_F 256
#define HD 128   // HEADS * OUT_FEATS
#define BM 64

using f32x4 = __attribute__((ext_vector_type(4))) float;
using s8v   = __attribute__((ext_vector_type(8))) short;

__device__ __forceinline__ short bf16rn(float x) {
  unsigned u = __builtin_bit_cast(unsigned, x);
  return (short)((u + 0x7FFFu + ((u >> 16) & 1u)) >> 16);
}
__device__ __forceinline__ float bf16tof(short h) {
  unsigned u = ((unsigned)(unsigned short)h) << 16;
  return __builtin_bit_cast(float, u);
}

typedef const __attribute__((address_space(1))) void gvoid;
typedef __attribute__((address_space(3))) void lvoid;
__device__ __forceinline__ void gl_lds16(const void* g, char* l) {
  __builtin_amdgcn_global_load_lds((gvoid*)g, (lvoid*)l, 16, 0, 0);
}

// ---- one-time: W[256][128] -> Btp packed in MFMA fragment order ----
// 16B chunk (kt*4+lg)*128 + c  holds bf16 of W[kt*32+lg*8 .. +7][c]
__global__ __launch_bounds__(256) void prep_b(const float* __restrict__ W,
                                              short* __restrict__ Btp)
{
  int c = blockIdx.x;      // 0..127
  int k = threadIdx.x;     // 0..255
  int kt = k >> 5, lg = (k >> 3) & 3, j = k & 7;
  Btp[(((size_t)(kt * 4 + lg) * 128 + c) << 3) + j] = bf16rn(W[(size_t)k * HD + c]);
}

// ---- one-time: Xp packed: cols 0-3 = W@attn_l, 4-7 = W@attn_r, 8-15 = 0 ----
// 16B chunk kt*64 + lg*16 + c
__global__ __launch_bounds__(256) void prep_x(const float* __restrict__ W,
    const float* __restrict__ al, const float* __restrict__ ar,
    short* __restrict__ Xp)
{
  int c = blockIdx.x;      // 0..15
  int k = threadIdx.x;     // 0..255
  float v = 0.f;
  if (c < 8) {
    int h = c & 3;
    const float* att = (c < 4) ? al : ar;
    #pragma unroll
    for (int d = 0; d < 32; d++)
      v += W[(size_t)k * HD + h * 32 + d] * att[h * 32 + d];
  }
  int kt = k >> 5, lg = (k >> 3) & 3, j = k & 7;
  Xp[(((size_t)kt * 64 + lg * 16 + c) << 3) + j] = bf16rn(v);
}

// ---- A staging: whole 64x256 f32 tile (contiguous 64KB of feat), XOR-swizzled source ----
// LDS row r at byte r*1024; 16B chunk c stored at slot c ^ (r&7) (involution).
__device__ __forceinline__ void stage_A(char* Asm, int wid, int lane,
                                        const float* feat, int rb, int M)
{
  #pragma unroll
  for (int s = 0; s < 16; s++) {
    const int o = wid + s * 4;          // tile row 0..63 (wave-uniform)
    int gr = rb + o; if (gr > M - 1) gr = M - 1;   // clamp tail (stores guarded)
    gl_lds16(feat + (size_t)gr * IN_F + ((lane ^ (o & 7)) << 2), Asm + o * 1024);
  }
}

// ---- GEMM (bf16x2 MFMA) + fused el/er: ft[M,128] = feat[M,256] @ W ----
// Block: 64x128, 4 waves of 32x64. Single-stage A in LDS (one barrier);
// B/X read directly from L2-resident packed tables.
__global__ __launch_bounds__(256) void gemm_mfma(const float* __restrict__ feat,
    const short* __restrict__ Btp, const short* __restrict__ Xp,
    float* __restrict__ ft, float* __restrict__ el, float* __restrict__ er, int M)
{
  __shared__ __align__(16) char lds[65536];   // A only -> 2 blocks/CU
  const int wid  = threadIdx.x >> 6;
  const int lane = threadIdx.x & 63;
  const int lr = lane & 15;           // A row / B col within fragment
  const int lg = lane >> 4;           // k-octet / D row group
  const int wm = (wid >> 1) * 32;
  const int wn = (wid & 1) * 64;
  const int rb = blockIdx.x * BM;
  const bool doX = (wid & 1) == 0;    // left-column waves also compute el/er

  f32x4 acc[2][4];
  f32x4 accx[2];
  #pragma unroll
  for (int mi = 0; mi < 2; mi++) {
    accx[mi] = (f32x4){0.f, 0.f, 0.f, 0.f};
    #pragma unroll
    for (int ni = 0; ni < 4; ni++) acc[mi][ni] = (f32x4){0.f, 0.f, 0.f, 0.f};
  }

  stage_A(lds, wid, lane, feat, rb, M);
  __syncthreads();

  #pragma unroll 4
  for (int kt = 0; kt < 8; ++kt) {
    s8v Bf[4];
    #pragma unroll
    for (int ni = 0; ni < 4; ni++)
      Bf[ni] = *(const s8v*)(Btp + (((size_t)(kt * 4 + lg) * 128 + wn + ni * 16 + lr) << 3));
    s8v Xf = *(const s8v*)(Xp + (((size_t)kt * 64 + lg * 16 + lr) << 3));

    #pragma unroll
    for (int mi = 0; mi < 2; mi++) {
      const int R = wm + mi * 16 + lr;
      const int cb = kt * 8 + lg * 2;
      const float4 a0 = *(const float4*)(lds + R * 1024 + (((cb + 0) ^ (R & 7)) << 4));
      const float4 a1 = *(const float4*)(lds + R * 1024 + (((cb + 1) ^ (R & 7)) << 4));
      const float av[8] = {a0.x, a0.y, a0.z, a0.w, a1.x, a1.y, a1.z, a1.w};
      s8v ah, alo;
      #pragma unroll
      for (int j = 0; j < 8; j++) {
        short h = bf16rn(av[j]);
        ah[j]  = h;
        alo[j] = bf16rn(av[j] - bf16tof(h));
      }
      #pragma unroll
      for (int ni = 0; ni < 4; ni++) {
        acc[mi][ni] = __builtin_amdgcn_mfma_f32_16x16x32_bf16(ah,  Bf[ni], acc[mi][ni], 0, 0, 0);
        acc[mi][ni] = __builtin_amdgcn_mfma_f32_16x16x32_bf16(alo, Bf[ni], acc[mi][ni], 0, 0, 0);
      }
      if (doX) {
        accx[mi] = __builtin_amdgcn_mfma_f32_16x16x32_bf16(ah,  Xf, accx[mi], 0, 0, 0);
        accx[mi] = __builtin_amdgcn_mfma_f32_16x16x32_bf16(alo, Xf, accx[mi], 0, 0, 0);
      }
    }
  }

  // D layout: col = lane&15, row = (lane>>4)*4 + reg
  #pragma unroll
  for (int mi = 0; mi < 2; mi++) {
    int rbase = rb + wm + mi * 16 + lg * 4;
    #pragma unroll
    for (int ni = 0; ni < 4; ni++) {
      int col = wn + ni * 16 + lr;
      #pragma unroll
      for (int r = 0; r < 4; r++) {
        int grow = rbase + r;
        if (grow < M) ft[(size_t)grow * HD + col] = acc[mi][ni][r];
      }
    }
    if (doX) {
      #pragma unroll
      for (int r = 0; r < 4; r++) {
        int grow = rbase + r;
        if (grow < M) {
          if (lr < 4)      el[(size_t)grow * 4 + lr]       = accx[mi][r];
          else if (lr < 8) er[(size_t)grow * 4 + (lr - 4)] = accx[mi][r];
        }
      }
    }
  }
}

// ---------------- CSR build ----------------
__global__ void deg_kernel(const int* __restrict__ dst, int* __restrict__ deg) {
  int i = blockIdx.x * blockDim.x + threadIdx.x;
  if (i < N_EDGES) atomicAdd(&deg[dst[i]], 1);
}

__global__ __launch_bounds__(256) void scanA(const int* __restrict__ deg,
    int* __restrict__ excl, int* __restrict__ partials, int n)
{
  __shared__ int s[256];
  int t = threadIdx.x;
  int base = blockIdx.x * 1024 + t * 4;
  int d0 = (base + 0 < n) ? deg[base + 0] : 0;
  int d1 = (base + 1 < n) ? deg[base + 1] : 0;
  int d2 = (base + 2 < n) ? deg[base + 2] : 0;
  int d3 = (base + 3 < n) ? deg[base + 3] : 0;
  int sum = d0 + d1 + d2 + d3;
  s[t] = sum; __syncthreads();
  for (int off = 1; off < 256; off <<= 1) {
    int x = 0; if (t >= off) x = s[t - off];
    __syncthreads(); s[t] += x; __syncthreads();
  }
  int e0 = s[t] - sum;
  if (base + 0 < n) excl[base + 0] = e0;
  if (base + 1 < n) excl[base + 1] = e0 + d0;
  if (base + 2 < n) excl[base + 2] = e0 + d0 + d1;
  if (base + 3 < n) excl[base + 3] = e0 + d0 + d1 + d2;
  if (t == 255) partials[blockIdx.x] = s[255];
}

__global__ void scanB(int* partials, int nb) {
  __shared__ int s[128];
  int t = threadIdx.x;
  int v = (t < nb) ? partials[t] : 0;
  s[t] = v; __syncthreads();
  for (int off = 1; off < 128; off <<= 1) {
    int x = 0; if (t >= off) x = s[t - off];
    __syncthreads(); s[t] += x; __syncthreads();
  }
  if (t < nb) partials[t] = s[t] - v;
}

__global__ __launch_bounds__(256) void scanC(int* __restrict__ row_ptr,
    const int* __restrict__ partials, int n, int E)
{
  int t = threadIdx.x;
  int base = blockIdx.x * 1024 + t * 4;
  int add = partials[blockIdx.x];
  #pragma unroll
  for (int j = 0; j < 4; j++) if (base + j < n) row_ptr[base + j] += add;
  if (blockIdx.x == 0 && t == 0) row_ptr[n] = E;
}

__global__ void scatter_kernel(const int* __restrict__ src, const int* __restrict__ dst,
                               const int* __restrict__ row_ptr,
                               int* __restrict__ cursor, int* __restrict__ usrc) {
  int e = blockIdx.x * blockDim.x + threadIdx.x;
  if (e >= N_EDGES) return;
  int d = dst[e];
  int pos = row_ptr[d] + atomicAdd(&cursor[d], 1);
  usrc[pos] = src[e];
}

// ---------------- fused online-softmax + aggregation: one wave per dst node ----------------
__global__ __launch_bounds__(256) void gat_node(const int* __restrict__ row_ptr,
    const int* __restrict__ usrc,
    const float* __restrict__ el, const float* __restrict__ er4,
    const float* __restrict__ ft, float* __restrict__ rst,
    float* __restrict__ lse, int n)
{
  __shared__ int   su[4][64];
  __shared__ float sex[4][64][4];
  const int w = threadIdx.x >> 6;
  const int lane = threadIdx.x & 63;
  const int v = blockIdx.x * 4 + w;
  if (v >= n) return;
  const int s0 = row_ptr[v];
  const int d  = row_ptr[v + 1] - s0;
  const int g  = lane >> 4;

  if (d == 0) {
    *(float2*)(rst + (size_t)v * HD + 2 * lane) = make_float2(0.f, 0.f);
    return;
  }

  const float4 erv = *(const float4*)(er4 + (size_t)v * 4);
  float m0 = -1e30f, m1 = -1e30f, m2 = -1e30f, m3 = -1e30f;
  float den = 0.f;
  float2 acc = make_float2(0.f, 0.f);

  for (int c0 = 0; c0 < d; c0 += 64) {
    const int cd = min(64, d - c0);
    float x0 = -1e30f, x1 = -1e30f, x2 = -1e30f, x3 = -1e30f;
    int u = 0;
    if (lane < cd) {
      u = usrc[s0 + c0 + lane];
      const float4 elv = *(const float4*)(el + (size_t)u * 4);
      x0 = elv.x + erv.x; x0 = x0 > 0.f ? x0 : 0.2f * x0;
      x1 = elv.y + erv.y; x1 = x1 > 0.f ? x1 : 0.2f * x1;
      x2 = elv.z + erv.z; x2 = x2 > 0.f ? x2 : 0.2f * x2;
      x3 = elv.w + erv.w; x3 = x3 > 0.f ? x3 : 0.2f * x3;
    }
    su[w][lane] = u;
    float n0 = x0, n1 = x1, n2 = x2, n3 = x3;
    #pragma unroll
    for (int off = 32; off >= 1; off >>= 1) {
      n0 = fmaxf(n0, __shfl_xor(n0, off));
      n1 = fmaxf(n1, __shfl_xor(n1, off));
      n2 = fmaxf(n2, __shfl_xor(n2, off));
      n3 = fmaxf(n3, __shfl_xor(n3, off));
    }
    n0 = fmaxf(n0, m0); n1 = fmaxf(n1, m1); n2 = fmaxf(n2, m2); n3 = fmaxf(n3, m3);
    float e0 = __expf(x0 - n0), e1 = __expf(x1 - n1);
    float e2 = __expf(x2 - n2), e3 = __expf(x3 - n3);
    sex[w][lane][0] = e0; sex[w][lane][1] = e1;
    sex[w][lane][2] = e2; sex[w][lane][3] = e3;
    float mg = g == 0 ? m0 : g == 1 ? m1 : g == 2 ? m2 : m3;
    float ng = g == 0 ? n0 : g == 1 ? n1 : g == 2 ? n2 : n3;
    float scale = __expf(mg - ng);
    den *= scale; acc.x *= scale; acc.y *= scale;
    m0 = n0; m1 = n1; m2 = n2; m3 = n3;
    asm volatile("s_waitcnt lgkmcnt(0)" ::: "memory");
    #pragma unroll 4
    for (int j = 0; j < cd; ++j) {
      int uu = su[w][j];
      float wgt = sex[w][j][g];
      float2 f = *(const float2*)(ft + (size_t)uu * HD + 2 * lane);
      den += wgt;
      acc.x += wgt * f.x; acc.y += wgt * f.y;
    }
  }
  *(float2*)(rst + (size_t)v * HD + 2 * lane) = make_float2(acc.x / den, acc.y / den);
  if ((lane & 15) == 0) {
    float mg = g == 0 ? m0 : g == 1 ? m1 : g == 2 ? m2 : m3;
    lse[(size_t)v * 4 + g] = mg + __logf(den);
  }
}

// edge-parallel: a[e][h] = exp(leaky(el[src]+er[dst]) - lse[dst][h])
__global__ void norm_kernel(const int* __restrict__ src, const int* __restrict__ dst,
                            const float* __restrict__ el, const float* __restrict__ er,
                            const float* __restrict__ lse, float* __restrict__ a, int E)
{
  int i = blockIdx.x * blockDim.x + threadIdx.x;
  if (i >= E) return;
  int u = src[i], v = dst[i];
  const float4 elv = *(const float4*)(el + (size_t)u * 4);
  const float4 erv = *(const float4*)(er + (size_t)v * 4);
  const float4 ls  = *(const float4*)(lse + (size_t)v * 4);
  float x0 = elv.x + erv.x; x0 = x0 > 0.f ? x0 : 0.2f * x0;
  float x1 = elv.y + erv.y; x1 = x1 > 0.f ? x1 : 0.2f * x1;
  float x2 = elv.z + erv.z; x2 = x2 > 0.f ? x2 : 0.2f * x2;
  float x3 = elv.w + erv.w; x3 = x3 > 0.f ? x3 : 0.2f * x3;
  float4 o;
  o.x = __expf(x0 - ls.x); o.y = __expf(x1 - ls.y);
  o.z = __expf(x2 - ls.z); o.w = __expf(x3 - ls.w);
  *(float4*)(a + (size_t)i * 4) = o;
}

extern "C" void kernel_launch(void* const* d_in, const int* in_sizes, int n_in,
                              void* d_out, int out_size, void* d_ws, size_t ws_size,
                              hipStream_t stream)
{
  const float* feat = (const float*)d_in[0];
  const float* W    = (const float*)d_in[1];
  const float* al   = (const float*)d_in[2];
  const float* ar   = (const float*)d_in[3];
  const int*   src  = (const int*)d_in[4];
  const int*   dst  = (const int*)d_in[5];
  float* rst   = (float*)d_out;
  float* a_out = rst + (size_t)N_NODES * HD;

  char* w = (char*)d_ws;
  auto alloc = [&](size_t bytes) { char* p = w; w += (bytes + 255) & ~(size_t)255; return p; };
  float* ft      = (float*)alloc((size_t)N_NODES * HD * 4);
  float* el      = (float*)alloc((size_t)N_NODES * 4 * 4);
  float* er      = (float*)alloc((size_t)N_NODES * 4 * 4);
  float* lse     = (float*)alloc((size_t)N_NODES * 4 * 4);
  int*   deg     = (int*)alloc((size_t)N_NODES * 4);
  int*   row_ptr = (int*)alloc(((size_t)N_NODES + 1) * 4);
  int*   cursor  = (int*)alloc((size_t)N_NODES * 4);
  int*   partials= (int*)alloc(1024);
  int*   usrc    = (int*)alloc((size_t)N_EDGES * 4);
  short* Btp     = (short*)alloc((size_t)HD * IN_F * 2);
  short* Xp      = (short*)alloc((size_t)16 * IN_F * 2);

  hipMemsetAsync(deg, 0, N_NODES * 4, stream);
  hipMemsetAsync(cursor, 0, N_NODES * 4, stream);

  prep_b<<<128, 256, 0, stream>>>(W, Btp);
  prep_x<<<16, 256, 0, stream>>>(W, al, ar, Xp);
  gemm_mfma<<<(N_NODES + BM - 1) / BM, 256, 0, stream>>>(feat, Btp, Xp, ft, el, er, N_NODES);
  deg_kernel<<<(N_EDGES + 255) / 256, 256, 0, stream>>>(dst, deg);
  scanA<<<98, 256, 0, stream>>>(deg, row_ptr, partials, N_NODES);
  scanB<<<1, 128, 0, stream>>>(partials, 98);
  scanC<<<98, 256, 0, stream>>>(row_ptr, partials, N_NODES, N_EDGES);
  scatter_kernel<<<(N_EDGES + 255) / 256, 256, 0, stream>>>(src, dst, row_ptr, cursor, usrc);
  gat_node<<<(N_NODES + 3) / 4, 256, 0, stream>>>(row_ptr, usrc, el, er, ft, rst, lse, N_NODES);
  norm_kernel<<<(N_EDGES + 255) / 256, 256, 0, stream>>>(src, dst, el, er, lse, a_out, N_EDGES);
}